// Round 14
// baseline (89.233 us; speedup 1.0000x reference)
//
#include <hip/hip_runtime.h>

#define LOSS_EPS 0.001f
#define EPS_PAR 1e-12f
#define EPS_PT 1e-12f

typedef float f32x2 __attribute__((ext_vector_type(2)));
typedef int   i32x2 __attribute__((ext_vector_type(2)));

__device__ __forceinline__ f32x2 vmin2(f32x2 a, f32x2 b) { return __builtin_elementwise_min(a, b); }
__device__ __forceinline__ f32x2 vmax2(f32x2 a, f32x2 b) { return __builtin_elementwise_max(a, b); }
__device__ __forceinline__ f32x2 vclamp01(f32x2 v) {
    return vmin2(vmax2(v, (f32x2)0.0f), (f32x2)1.0f);
}
__device__ __forceinline__ f32x2 vrcp(f32x2 x) {
    f32x2 r; r.x = __builtin_amdgcn_rcpf(x.x); r.y = __builtin_amdgcn_rcpf(x.y); return r;
}
// bit-select: m ? a : b per component (R6-proven; ternary form regressed in R9)
__device__ __forceinline__ f32x2 vsel(i32x2 m, f32x2 a, f32x2 b) {
    i32x2 ai = __builtin_bit_cast(i32x2, a);
    i32x2 bi = __builtin_bit_cast(i32x2, b);
    i32x2 r = (ai & m) | (bi & ~m);
    return __builtin_bit_cast(f32x2, r);
}

struct V3p { f32x2 x, y, z; };
__device__ __forceinline__ V3p operator-(V3p a, V3p b) { return {a.x - b.x, a.y - b.y, a.z - b.z}; }
__device__ __forceinline__ V3p operator+(V3p a, V3p b) { return {a.x + b.x, a.y + b.y, a.z + b.z}; }
__device__ __forceinline__ V3p operator*(f32x2 s, V3p a) { return {s * a.x, s * a.y, s * a.z}; }
__device__ __forceinline__ f32x2 dotp(V3p a, V3p b) { return a.x * b.x + a.y * b.y + a.z * b.z; }

__device__ __forceinline__ f32x2 edge_edge_d2(V3p p1, V3p d1, V3p p2, V3p d2,
                                              f32x2 a, f32x2 e, f32x2 ra, f32x2 re) {
    V3p r = p1 - p2;
    f32x2 f = dotp(d2, r);
    f32x2 b = dotp(d1, d2);
    f32x2 c = dotp(d1, r);
    f32x2 denom = a * e - b * b;
    i32x2 par = denom < (f32x2)EPS_PAR;
    f32x2 rd = vrcp(vsel(par, (f32x2)1.0f, denom));
    f32x2 s = (b * f - c * e) * rd;
    f32x2 t = (a * f - b * c) * rd;
    s = vsel(par, (f32x2)0.0f, s);
    f32x2 s_cl = vclamp01(s);
    f32x2 t_cl = vclamp01(t);
    i32x2 rec_t = (s_cl != s) | par;
    V3p r_new = r + s_cl * d1;
    f32x2 t_new = vclamp01(dotp(r_new, d2) * re);
    f32x2 t_fin = vsel(rec_t, t_new, t_cl);
    i32x2 rec_s = (t_cl != t) & ~par & (s_cl == s);
    V3p r_new2 = r - t_fin * d2;
    f32x2 s_new = (-dotp(r_new2, d1)) * ra;
    f32x2 s_fin = vsel(rec_s, vclamp01(s_new), s_cl);
    V3p c1 = p1 + s_fin * d1;
    V3p c2 = p2 + t_fin * d2;
    V3p diff = c1 - c2;
    return dotp(diff, diff);
}

__device__ __forceinline__ f32x2 ptri3_min_d2(V3p p0, V3p p1, V3p p2,
                                              V3p v0, V3p v1, V3p v2) {
    V3p e0 = v1 - v0;
    V3p e1 = v2 - v0;
    V3p e2t = v2 - v1;
    f32x2 a  = vmax2(dotp(e0, e0), (f32x2)EPS_PT);
    f32x2 b  = dotp(e0, e1);
    f32x2 c  = vmax2(dotp(e1, e1), (f32x2)EPS_PT);
    f32x2 a2 = vmax2(dotp(e2t, e2t), (f32x2)EPS_PT);
    f32x2 det = vmax2(a * c - b * b, (f32x2)EPS_PT);
    f32x2 ra = vrcp(a), rc = vrcp(c), ra2 = vrcp(a2), rdet = vrcp(det);

    f32x2 best = (f32x2)1e30f;
    V3p pts[3] = {p0, p1, p2};
#pragma unroll
    for (int k = 0; k < 3; ++k) {
        V3p p = pts[k];
        V3p w = p - v0;
        f32x2 d = dotp(e0, w);
        f32x2 e = dotp(e1, w);
        f32x2 f = dotp(w, w);
        f32x2 s = b * e - c * d;
        f32x2 t = b * d - a * e;
        i32x2 in_face = (s >= (f32x2)0.0f) & (t >= (f32x2)0.0f) & ((s + t) <= det);
        f32x2 s01 = vclamp01(d * ra);
        V3p u01 = w - s01 * e0;
        f32x2 d2_e01 = dotp(u01, u01);
        f32x2 t02 = vclamp01(e * rc);
        V3p u02 = w - t02 * e1;
        f32x2 d2_e02 = dotp(u02, u02);
        V3p w2 = p - v1;
        f32x2 dd2 = dotp(e2t, w2);
        f32x2 u12 = vclamp01(dd2 * ra2);
        V3p u12v = w2 - u12 * e2t;
        f32x2 d2_e12 = dotp(u12v, u12v);
        f32x2 d2_face = vmax2((f * det - (d * s + e * t)) * rdet, (f32x2)0.0f);
        f32x2 d2_edge = vmin2(vmin2(d2_e01, d2_e02), d2_e12);
        best = vmin2(best, vsel(in_face, d2_face, d2_edge));
    }
    return best;
}

// Packed body operating on pre-transposed T arrays (component 0 = even pair, 1 = odd pair).
__device__ __forceinline__ f32x2 body_from_T(const f32x2 T1[9], const f32x2 T2[9], f32x2 vmask) {
    V3p A[3]  = { {T1[0], T1[1], T1[2]}, {T1[3], T1[4], T1[5]}, {T1[6], T1[7], T1[8]} };
    V3p Ac[3] = { {T1[0], T1[3], T1[6]}, {T1[1], T1[4], T1[7]}, {T1[2], T1[5], T1[8]} };
    V3p B[3]  = { {T2[0], T2[1], T2[2]}, {T2[3], T2[4], T2[5]}, {T2[6], T2[7], T2[8]} };
    V3p Bc[3] = { {T2[0], T2[3], T2[6]}, {T2[1], T2[4], T2[7]}, {T2[2], T2[5], T2[8]} };

    f32x2 mind2 = (f32x2)1e30f;
    mind2 = vmin2(mind2, ptri3_min_d2(A[0], A[1], A[2], Bc[0], Bc[1], Bc[2]));
    mind2 = vmin2(mind2, ptri3_min_d2(B[0], B[1], B[2], Ac[0], Ac[1], Ac[2]));

    V3p dA[3] = { A[1] - A[0], A[2] - A[1], A[0] - A[2] };
    V3p dB[3] = { B[1] - B[0], B[2] - B[1], B[0] - B[2] };
    f32x2 la[3], lb[3], rla[3], rlb[3];
#pragma unroll
    for (int k = 0; k < 3; ++k) {
        la[k] = dotp(dA[k], dA[k]); rla[k] = vrcp(la[k]);
        lb[k] = dotp(dB[k], dB[k]); rlb[k] = vrcp(lb[k]);
    }
#pragma unroll
    for (int ii = 0; ii < 3; ++ii) {
#pragma unroll
        for (int jj = 0; jj < 3; ++jj) {
            mind2 = vmin2(mind2, edge_edge_d2(A[ii], dA[ii], B[jj], dB[jj],
                                              la[ii], lb[jj], rla[ii], rlb[jj]));
        }
    }
    f32x2 dist;
    dist.x = __builtin_sqrtf(mind2.x);
    dist.y = __builtin_sqrtf(mind2.y);
    return vmax2((f32x2)LOSS_EPS - dist, (f32x2)0.0f) * vmask;
}

// Block reduce + global accumulate; LAST block to finish writes the final loss (R9-proven).
__device__ __forceinline__ void block_reduce_atomic_fused(float pen, float val, float* ws,
                                                          float* out, unsigned nwg) {
#pragma unroll
    for (int off = 32; off > 0; off >>= 1) {
        pen += __shfl_down(pen, off);
        val += __shfl_down(val, off);
    }
    __shared__ float sp[4], sv[4];
    int wid = threadIdx.x >> 6;
    if ((threadIdx.x & 63) == 0) { sp[wid] = pen; sv[wid] = val; }
    __syncthreads();
    if (threadIdx.x == 0) {
        atomicAdd(&ws[0], sp[0] + sp[1] + sp[2] + sp[3]);
        atomicAdd(&ws[1], sv[0] + sv[1] + sv[2] + sv[3]);
        __threadfence();                              // publish sums before counter
        unsigned done = atomicAdd((unsigned*)(ws + 2), 1u);
        if (done == nwg - 1) {                        // last block: finalize
            float p = atomicAdd(&ws[0], 0.0f);        // device-scope atomic read
            float v = atomicAdd(&ws[1], 0.0f);
            out[0] = p / fmaxf(v, 1.0f);
        }
    }
}

// Repack 9-float (36B) triangles into 64B-aligned slots; vectorized loads;
// zeroes the 3 accumulators (no separate memset dispatch).
__global__ void __launch_bounds__(256)
prep_kernel(const float* __restrict__ tris, float4* __restrict__ pack,
            float* __restrict__ ws, int ntri) {
    int g = blockIdx.x * 256 + threadIdx.x;
    if (g == 0) { ws[0] = 0.0f; ws[1] = 0.0f; ((unsigned*)ws)[2] = 0u; }
    if (g >= ntri) return;
    const float* s = tris + (size_t)g * 9;
    float4 q0 = *(const float4*)(s);       // 4B-aligned dwordx4 (legal on gfx950)
    float4 q1 = *(const float4*)(s + 4);
    float  q2 = s[8];
    float4* d = pack + (size_t)g * 4;
    d[0] = q0;
    d[1] = q1;
    d[2] = make_float4(q2, 0.0f, 0.0f, 0.0f);
}

#define PPT 8                         // pairs per thread (4 packed bodies) — R6-proven
#define PAIRS_PER_BLOCK (256 * PPT)   // 2048

__global__ void __launch_bounds__(256)
pen_loss_pipe2(const float4* __restrict__ pack, const int* __restrict__ idx,
               float* __restrict__ ws, float* __restrict__ out,
               int npairs, int F, int P, int nwg) {
    // Bijective XCD chunk swizzle (m204).
    int pb = blockIdx.x;
    int x = pb & 7, j = pb >> 3;
    int q8 = nwg >> 3, r8 = nwg & 7;
    int start = (x < r8) ? x * (q8 + 1) : r8 * (q8 + 1) + (x - r8) * q8;
    int lb = start + j;
    int tid = (int)threadIdx.x;
    int p0 = lb * PAIRS_PER_BLOCK + tid;

    // 1) All idx loads upfront (coalesced, nontemporal: keep L2 for the table).
    int o1[PPT], o2[PPT];
    float vm[PPT];
#pragma unroll
    for (int k = 0; k < PPT; ++k) {
        int p = p0 + k * 256;
        int pc = min(p, npairs - 1);
        long long pr = __builtin_nontemporal_load((const long long*)idx + pc);
        int rx = (int)(pr & 0xffffffffLL);
        int ry = (int)(pr >> 32);
        vm[k] = (p < npairs && rx >= 0) ? 1.0f : 0.0f;
        int b = (pc >= P) + (pc >= 2 * P) + (pc >= 3 * P);   // pc / P without idiv
        int base = b * F;
        o1[k] = (base + max(rx, 0)) * 4;
        o2[k] = (base + max(ry, 0)) * 4;
    }

    // Single 12-quad staging buffer: PACKT consumes it, next LOADBODY refills it
    // while the ~1400-cycle packed body runs. All indices static (rule #20).
    float4 qb_[12];

#define LOADBODY(m) do {                                                      \
        const int ev = 2 * (m), od = 2 * (m) + 1;                             \
        qb_[0] = pack[o1[ev]];     qb_[1] = pack[o1[ev] + 1];                 \
        qb_[2] = pack[o1[ev] + 2]; qb_[3] = pack[o2[ev]];                     \
        qb_[4] = pack[o2[ev] + 1]; qb_[5] = pack[o2[ev] + 2];                 \
        qb_[6] = pack[o1[od]];     qb_[7] = pack[o1[od] + 1];                 \
        qb_[8] = pack[o1[od] + 2]; qb_[9] = pack[o2[od]];                     \
        qb_[10] = pack[o2[od] + 1]; qb_[11] = pack[o2[od] + 2];               \
    } while (0)

#define PACKT(T1, T2) do {                                                    \
        T1[0] = (f32x2){qb_[0].x, qb_[6].x}; T1[1] = (f32x2){qb_[0].y, qb_[6].y}; \
        T1[2] = (f32x2){qb_[0].z, qb_[6].z}; T1[3] = (f32x2){qb_[0].w, qb_[6].w}; \
        T1[4] = (f32x2){qb_[1].x, qb_[7].x}; T1[5] = (f32x2){qb_[1].y, qb_[7].y}; \
        T1[6] = (f32x2){qb_[1].z, qb_[7].z}; T1[7] = (f32x2){qb_[1].w, qb_[7].w}; \
        T1[8] = (f32x2){qb_[2].x, qb_[8].x};                                      \
        T2[0] = (f32x2){qb_[3].x, qb_[9].x}; T2[1] = (f32x2){qb_[3].y, qb_[9].y}; \
        T2[2] = (f32x2){qb_[3].z, qb_[9].z}; T2[3] = (f32x2){qb_[3].w, qb_[9].w}; \
        T2[4] = (f32x2){qb_[4].x, qb_[10].x}; T2[5] = (f32x2){qb_[4].y, qb_[10].y}; \
        T2[6] = (f32x2){qb_[4].z, qb_[10].z}; T2[7] = (f32x2){qb_[4].w, qb_[10].w}; \
        T2[8] = (f32x2){qb_[5].x, qb_[11].x};                                     \
    } while (0)

    LOADBODY(0);
    f32x2 pen2 = (f32x2)0.0f;
#pragma unroll
    for (int m = 0; m < PPT / 2; ++m) {
        f32x2 T1[9], T2[9];
        PACKT(T1, T2);                     // consumes qb_ (waits loads), frees it
        if (m < PPT / 2 - 1) LOADBODY(m + 1);  // next body's gathers fly under the body
        f32x2 vmm = {vm[2 * m], vm[2 * m + 1]};
        pen2 += body_from_T(T1, T2, vmm);
    }
#undef LOADBODY
#undef PACKT

    float pen_s = pen2.x + pen2.y;
    float val_s = 0.0f;
#pragma unroll
    for (int k = 0; k < PPT; ++k) val_s += vm[k];
    block_reduce_atomic_fused(pen_s, val_s, ws, out, (unsigned)nwg);
}

// -------- fallback (workspace too small): R11-style direct single kernel --------
__global__ void __launch_bounds__(256)
pen_loss_direct(const float* __restrict__ tris, const int* __restrict__ idx,
                float* __restrict__ ws, float* __restrict__ out,
                int npairs, int F, int P, int nwg) {
    int pb = blockIdx.x;
    int x = pb & 7, j = pb >> 3;
    int q8 = nwg >> 3, r8 = nwg & 7;
    int start = (x < r8) ? x * (q8 + 1) : r8 * (q8 + 1) + (x - r8) * q8;
    int lb = start + j;
    int tid = (int)threadIdx.x;
    int p0 = lb * PAIRS_PER_BLOCK + tid;

    int o1[PPT], o2[PPT];
    float vm[PPT];
#pragma unroll
    for (int k = 0; k < PPT; ++k) {
        int p = p0 + k * 256;
        int pc = min(p, npairs - 1);
        long long pr = __builtin_nontemporal_load((const long long*)idx + pc);
        int rx = (int)(pr & 0xffffffffLL);
        int ry = (int)(pr >> 32);
        vm[k] = (p < npairs && rx >= 0) ? 1.0f : 0.0f;
        int b = (pc >= P) + (pc >= 2 * P) + (pc >= 3 * P);
        int base = b * F;
        o1[k] = (base + max(rx, 0)) * 9;
        o2[k] = (base + max(ry, 0)) * 9;
    }

    float4 qAe0, qAe1, qBe0, qBe1, qAo0, qAo1, qBo0, qBo1;
    float  sAe, sBe, sAo, sBo;

#define LOADBODY(m) do {                                                      \
        const int ev = 2 * (m), od = 2 * (m) + 1;                             \
        qAe0 = *(const float4*)(tris + o1[ev]);                               \
        qAe1 = *(const float4*)(tris + o1[ev] + 4);                           \
        sAe  = tris[o1[ev] + 8];                                              \
        qBe0 = *(const float4*)(tris + o2[ev]);                               \
        qBe1 = *(const float4*)(tris + o2[ev] + 4);                           \
        sBe  = tris[o2[ev] + 8];                                              \
        qAo0 = *(const float4*)(tris + o1[od]);                               \
        qAo1 = *(const float4*)(tris + o1[od] + 4);                           \
        sAo  = tris[o1[od] + 8];                                              \
        qBo0 = *(const float4*)(tris + o2[od]);                               \
        qBo1 = *(const float4*)(tris + o2[od] + 4);                           \
        sBo  = tris[o2[od] + 8];                                              \
    } while (0)

#define PACKT(T1, T2) do {                                                    \
        T1[0] = (f32x2){qAe0.x, qAo0.x}; T1[1] = (f32x2){qAe0.y, qAo0.y};     \
        T1[2] = (f32x2){qAe0.z, qAo0.z}; T1[3] = (f32x2){qAe0.w, qAo0.w};     \
        T1[4] = (f32x2){qAe1.x, qAo1.x}; T1[5] = (f32x2){qAe1.y, qAo1.y};     \
        T1[6] = (f32x2){qAe1.z, qAo1.z}; T1[7] = (f32x2){qAe1.w, qAo1.w};     \
        T1[8] = (f32x2){sAe, sAo};                                            \
        T2[0] = (f32x2){qBe0.x, qBo0.x}; T2[1] = (f32x2){qBe0.y, qBo0.y};     \
        T2[2] = (f32x2){qBe0.z, qBo0.z}; T2[3] = (f32x2){qBe0.w, qBo0.w};     \
        T2[4] = (f32x2){qBe1.x, qBo1.x}; T2[5] = (f32x2){qBe1.y, qBo1.y};     \
        T2[6] = (f32x2){qBe1.z, qBo1.z}; T2[7] = (f32x2){qBe1.w, qBo1.w};     \
        T2[8] = (f32x2){sBe, sBo};                                            \
    } while (0)

    LOADBODY(0);
    f32x2 pen2 = (f32x2)0.0f;
#pragma unroll
    for (int m = 0; m < PPT / 2; ++m) {
        f32x2 T1[9], T2[9];
        PACKT(T1, T2);
        if (m < PPT / 2 - 1) LOADBODY(m + 1);
        f32x2 vmm = {vm[2 * m], vm[2 * m + 1]};
        pen2 += body_from_T(T1, T2, vmm);
    }
#undef LOADBODY
#undef PACKT

    float pen_s = pen2.x + pen2.y;
    float val_s = 0.0f;
#pragma unroll
    for (int k = 0; k < PPT; ++k) val_s += vm[k];
    block_reduce_atomic_fused(pen_s, val_s, ws, out, (unsigned)nwg);
}

extern "C" void kernel_launch(void* const* d_in, const int* in_sizes, int n_in,
                              void* d_out, int out_size, void* d_ws, size_t ws_size,
                              hipStream_t stream) {
    const float* tris = (const float*)d_in[0];
    const int* idx = (const int*)d_in[1];
    float* out = (float*)d_out;
    float* ws = (float*)d_ws;

    const int B = 4;
    int F = in_sizes[0] / (B * 9);      // 50000
    int npairs = in_sizes[1] / 2;       // 2,000,000
    int P = npairs / B;                 // 500,000
    int ntri = B * F;                   // 200,000
    int nwg = (npairs + PAIRS_PER_BLOCK - 1) / PAIRS_PER_BLOCK;   // 977

    size_t need = 256 + (size_t)ntri * 64;
    if (ws_size >= need) {
        float4* pack = (float4*)((char*)d_ws + 256);
        prep_kernel<<<(ntri + 255) / 256, 256, 0, stream>>>(tris, pack, ws, ntri);
        pen_loss_pipe2<<<nwg, 256, 0, stream>>>(pack, idx, ws, out,
                                                npairs, F, P, nwg);
    } else {
        hipMemsetAsync(d_ws, 0, 12, stream);
        pen_loss_direct<<<nwg, 256, 0, stream>>>(tris, idx, ws, out,
                                                 npairs, F, P, nwg);
    }
    // finalize fused into the last block of the main kernel
}

// Round 15
// 62.536 us; speedup vs baseline: 1.4269x; 1.4269x over previous
//
#include <hip/hip_runtime.h>

#define LOSS_EPS 0.001f
#define EPS_PAR 1e-12f
#define EPS_PT 1e-12f

typedef float f32x2 __attribute__((ext_vector_type(2)));
typedef int   i32x2 __attribute__((ext_vector_type(2)));

__device__ __forceinline__ f32x2 vmin2(f32x2 a, f32x2 b) { return __builtin_elementwise_min(a, b); }
__device__ __forceinline__ f32x2 vmax2(f32x2 a, f32x2 b) { return __builtin_elementwise_max(a, b); }
__device__ __forceinline__ f32x2 vclamp01(f32x2 v) {
    return vmin2(vmax2(v, (f32x2)0.0f), (f32x2)1.0f);
}
__device__ __forceinline__ f32x2 vrcp(f32x2 x) {
    f32x2 r; r.x = __builtin_amdgcn_rcpf(x.x); r.y = __builtin_amdgcn_rcpf(x.y); return r;
}
// bit-select: m ? a : b per component (R6-proven form)
__device__ __forceinline__ f32x2 vsel(i32x2 m, f32x2 a, f32x2 b) {
    i32x2 ai = __builtin_bit_cast(i32x2, a);
    i32x2 bi = __builtin_bit_cast(i32x2, b);
    i32x2 r = (ai & m) | (bi & ~m);
    return __builtin_bit_cast(f32x2, r);
}

struct V3p { f32x2 x, y, z; };
__device__ __forceinline__ V3p operator-(V3p a, V3p b) { return {a.x - b.x, a.y - b.y, a.z - b.z}; }
__device__ __forceinline__ V3p operator+(V3p a, V3p b) { return {a.x + b.x, a.y + b.y, a.z + b.z}; }
__device__ __forceinline__ V3p operator*(f32x2 s, V3p a) { return {s * a.x, s * a.y, s * a.z}; }
__device__ __forceinline__ f32x2 dotp(V3p a, V3p b) { return a.x * b.x + a.y * b.y + a.z * b.z; }

__device__ __forceinline__ f32x2 edge_edge_d2(V3p p1, V3p d1, V3p p2, V3p d2,
                                              f32x2 a, f32x2 e, f32x2 ra, f32x2 re) {
    V3p r = p1 - p2;
    f32x2 f = dotp(d2, r);
    f32x2 b = dotp(d1, d2);
    f32x2 c = dotp(d1, r);
    f32x2 denom = a * e - b * b;
    i32x2 par = denom < (f32x2)EPS_PAR;
    f32x2 rd = vrcp(vsel(par, (f32x2)1.0f, denom));
    f32x2 s = (b * f - c * e) * rd;
    f32x2 t = (a * f - b * c) * rd;
    s = vsel(par, (f32x2)0.0f, s);
    f32x2 s_cl = vclamp01(s);
    f32x2 t_cl = vclamp01(t);
    i32x2 rec_t = (s_cl != s) | par;
    V3p r_new = r + s_cl * d1;
    f32x2 t_new = vclamp01(dotp(r_new, d2) * re);
    f32x2 t_fin = vsel(rec_t, t_new, t_cl);
    i32x2 rec_s = (t_cl != t) & ~par & (s_cl == s);
    V3p r_new2 = r - t_fin * d2;
    f32x2 s_new = (-dotp(r_new2, d1)) * ra;
    f32x2 s_fin = vsel(rec_s, vclamp01(s_new), s_cl);
    V3p c1 = p1 + s_fin * d1;
    V3p c2 = p2 + t_fin * d2;
    V3p diff = c1 - c2;
    return dotp(diff, diff);
}

__device__ __forceinline__ f32x2 ptri3_min_d2(V3p p0, V3p p1, V3p p2,
                                              V3p v0, V3p v1, V3p v2) {
    V3p e0 = v1 - v0;
    V3p e1 = v2 - v0;
    V3p e2t = v2 - v1;
    f32x2 a  = vmax2(dotp(e0, e0), (f32x2)EPS_PT);
    f32x2 b  = dotp(e0, e1);
    f32x2 c  = vmax2(dotp(e1, e1), (f32x2)EPS_PT);
    f32x2 a2 = vmax2(dotp(e2t, e2t), (f32x2)EPS_PT);
    f32x2 det = vmax2(a * c - b * b, (f32x2)EPS_PT);
    f32x2 ra = vrcp(a), rc = vrcp(c), ra2 = vrcp(a2), rdet = vrcp(det);

    f32x2 best = (f32x2)1e30f;
    V3p pts[3] = {p0, p1, p2};
#pragma unroll
    for (int k = 0; k < 3; ++k) {
        V3p p = pts[k];
        V3p w = p - v0;
        f32x2 d = dotp(e0, w);
        f32x2 e = dotp(e1, w);
        f32x2 f = dotp(w, w);
        f32x2 s = b * e - c * d;
        f32x2 t = b * d - a * e;
        i32x2 in_face = (s >= (f32x2)0.0f) & (t >= (f32x2)0.0f) & ((s + t) <= det);
        f32x2 s01 = vclamp01(d * ra);
        V3p u01 = w - s01 * e0;
        f32x2 d2_e01 = dotp(u01, u01);
        f32x2 t02 = vclamp01(e * rc);
        V3p u02 = w - t02 * e1;
        f32x2 d2_e02 = dotp(u02, u02);
        V3p w2 = p - v1;
        f32x2 dd2 = dotp(e2t, w2);
        f32x2 u12 = vclamp01(dd2 * ra2);
        V3p u12v = w2 - u12 * e2t;
        f32x2 d2_e12 = dotp(u12v, u12v);
        f32x2 d2_face = vmax2((f * det - (d * s + e * t)) * rdet, (f32x2)0.0f);
        f32x2 d2_edge = vmin2(vmin2(d2_e01, d2_e02), d2_e12);
        best = vmin2(best, vsel(in_face, d2_face, d2_edge));
    }
    return best;
}

// Packed body operating on pre-transposed T arrays (component 0 = even pair, 1 = odd pair).
__device__ __forceinline__ f32x2 body_from_T(const f32x2 T1[9], const f32x2 T2[9], f32x2 vmask) {
    V3p A[3]  = { {T1[0], T1[1], T1[2]}, {T1[3], T1[4], T1[5]}, {T1[6], T1[7], T1[8]} };
    V3p Ac[3] = { {T1[0], T1[3], T1[6]}, {T1[1], T1[4], T1[7]}, {T1[2], T1[5], T1[8]} };
    V3p B[3]  = { {T2[0], T2[1], T2[2]}, {T2[3], T2[4], T2[5]}, {T2[6], T2[7], T2[8]} };
    V3p Bc[3] = { {T2[0], T2[3], T2[6]}, {T2[1], T2[4], T2[7]}, {T2[2], T2[5], T2[8]} };

    f32x2 mind2 = (f32x2)1e30f;
    mind2 = vmin2(mind2, ptri3_min_d2(A[0], A[1], A[2], Bc[0], Bc[1], Bc[2]));
    mind2 = vmin2(mind2, ptri3_min_d2(B[0], B[1], B[2], Ac[0], Ac[1], Ac[2]));

    V3p dA[3] = { A[1] - A[0], A[2] - A[1], A[0] - A[2] };
    V3p dB[3] = { B[1] - B[0], B[2] - B[1], B[0] - B[2] };
    f32x2 la[3], lb[3], rla[3], rlb[3];
#pragma unroll
    for (int k = 0; k < 3; ++k) {
        la[k] = dotp(dA[k], dA[k]); rla[k] = vrcp(la[k]);
        lb[k] = dotp(dB[k], dB[k]); rlb[k] = vrcp(lb[k]);
    }
#pragma unroll
    for (int ii = 0; ii < 3; ++ii) {
#pragma unroll
        for (int jj = 0; jj < 3; ++jj) {
            mind2 = vmin2(mind2, edge_edge_d2(A[ii], dA[ii], B[jj], dB[jj],
                                              la[ii], lb[jj], rla[ii], rlb[jj]));
        }
    }
    f32x2 dist;
    dist.x = __builtin_sqrtf(mind2.x);
    dist.y = __builtin_sqrtf(mind2.y);
    return vmax2((f32x2)LOSS_EPS - dist, (f32x2)0.0f) * vmask;
}

// Plain block reduce + two global atomics. NO fence, NO counter (fence cost ~13us, R14).
__device__ __forceinline__ void block_reduce_atomic(float pen, float val, float* ws) {
#pragma unroll
    for (int off = 32; off > 0; off >>= 1) {
        pen += __shfl_down(pen, off);
        val += __shfl_down(val, off);
    }
    __shared__ float sp[4], sv[4];
    int wid = threadIdx.x >> 6;
    if ((threadIdx.x & 63) == 0) { sp[wid] = pen; sv[wid] = val; }
    __syncthreads();
    if (threadIdx.x == 0) {
        atomicAdd(&ws[0], sp[0] + sp[1] + sp[2] + sp[3]);
        atomicAdd(&ws[1], sv[0] + sv[1] + sv[2] + sv[3]);
    }
}

#define PPT 8                         // pairs per thread (4 packed bodies) — R6-proven
#define PAIRS_PER_BLOCK (256 * PPT)   // 2048

// Direct gathers from the original 36B rows (R11-proven equal to packed-slot gathers).
__global__ void __launch_bounds__(256)
pen_loss_main(const float* __restrict__ tris, const int* __restrict__ idx,
              float* __restrict__ ws, int npairs, int F, int P, int nwg) {
    // Bijective XCD chunk swizzle (m204).
    int pb = blockIdx.x;
    int x = pb & 7, j = pb >> 3;
    int q8 = nwg >> 3, r8 = nwg & 7;
    int start = (x < r8) ? x * (q8 + 1) : r8 * (q8 + 1) + (x - r8) * q8;
    int lb = start + j;
    int tid = (int)threadIdx.x;
    int p0 = lb * PAIRS_PER_BLOCK + tid;

    // 1) All idx loads upfront (coalesced, nontemporal: keep L2 for the table).
    int o1[PPT], o2[PPT];
    float vm[PPT];
#pragma unroll
    for (int k = 0; k < PPT; ++k) {
        int p = p0 + k * 256;
        int pc = min(p, npairs - 1);
        long long pr = __builtin_nontemporal_load((const long long*)idx + pc);
        int rx = (int)(pr & 0xffffffffLL);
        int ry = (int)(pr >> 32);
        vm[k] = (p < npairs && rx >= 0) ? 1.0f : 0.0f;
        int b = (pc >= P) + (pc >= 2 * P) + (pc >= 3 * P);   // pc / P without idiv
        int base = b * F;
        o1[k] = (base + max(rx, 0)) * 9;
        o2[k] = (base + max(ry, 0)) * 9;
    }

    // Staging for one body (2 pairs): per triangle 2x dwordx4 + 1 dword.
    // PACKT consumes it; the next LOADBODY refills while the body computes.
    float4 qAe0, qAe1, qBe0, qBe1, qAo0, qAo1, qBo0, qBo1;
    float  sAe, sBe, sAo, sBo;

#define LOADBODY(m) do {                                                      \
        const int ev = 2 * (m), od = 2 * (m) + 1;                             \
        qAe0 = *(const float4*)(tris + o1[ev]);                               \
        qAe1 = *(const float4*)(tris + o1[ev] + 4);                           \
        sAe  = tris[o1[ev] + 8];                                              \
        qBe0 = *(const float4*)(tris + o2[ev]);                               \
        qBe1 = *(const float4*)(tris + o2[ev] + 4);                           \
        sBe  = tris[o2[ev] + 8];                                              \
        qAo0 = *(const float4*)(tris + o1[od]);                               \
        qAo1 = *(const float4*)(tris + o1[od] + 4);                           \
        sAo  = tris[o1[od] + 8];                                              \
        qBo0 = *(const float4*)(tris + o2[od]);                               \
        qBo1 = *(const float4*)(tris + o2[od] + 4);                           \
        sBo  = tris[o2[od] + 8];                                              \
    } while (0)

#define PACKT(T1, T2) do {                                                    \
        T1[0] = (f32x2){qAe0.x, qAo0.x}; T1[1] = (f32x2){qAe0.y, qAo0.y};     \
        T1[2] = (f32x2){qAe0.z, qAo0.z}; T1[3] = (f32x2){qAe0.w, qAo0.w};     \
        T1[4] = (f32x2){qAe1.x, qAo1.x}; T1[5] = (f32x2){qAe1.y, qAo1.y};     \
        T1[6] = (f32x2){qAe1.z, qAo1.z}; T1[7] = (f32x2){qAe1.w, qAo1.w};     \
        T1[8] = (f32x2){sAe, sAo};                                            \
        T2[0] = (f32x2){qBe0.x, qBo0.x}; T2[1] = (f32x2){qBe0.y, qBo0.y};     \
        T2[2] = (f32x2){qBe0.z, qBo0.z}; T2[3] = (f32x2){qBe0.w, qBo0.w};     \
        T2[4] = (f32x2){qBe1.x, qBo1.x}; T2[5] = (f32x2){qBe1.y, qBo1.y};     \
        T2[6] = (f32x2){qBe1.z, qBo1.z}; T2[7] = (f32x2){qBe1.w, qBo1.w};     \
        T2[8] = (f32x2){sBe, sBo};                                            \
    } while (0)

    LOADBODY(0);
    f32x2 pen2 = (f32x2)0.0f;
#pragma unroll
    for (int m = 0; m < PPT / 2; ++m) {
        f32x2 T1[9], T2[9];
        PACKT(T1, T2);                     // consumes staging (waits loads), frees it
        if (m < PPT / 2 - 1) LOADBODY(m + 1);  // next body's gathers fly under the body
        f32x2 vmm = {vm[2 * m], vm[2 * m + 1]};
        pen2 += body_from_T(T1, T2, vmm);
    }
#undef LOADBODY
#undef PACKT

    float pen_s = pen2.x + pen2.y;
    float val_s = 0.0f;
#pragma unroll
    for (int k = 0; k < PPT; ++k) val_s += vm[k];
    block_reduce_atomic(pen_s, val_s, ws);
}

__global__ void finalize_kernel(const float* __restrict__ ws, float* __restrict__ out) {
    out[0] = ws[0] / fmaxf(ws[1], 1.0f);
}

extern "C" void kernel_launch(void* const* d_in, const int* in_sizes, int n_in,
                              void* d_out, int out_size, void* d_ws, size_t ws_size,
                              hipStream_t stream) {
    const float* tris = (const float*)d_in[0];
    const int* idx = (const int*)d_in[1];
    float* out = (float*)d_out;
    float* ws = (float*)d_ws;

    const int B = 4;
    int F = in_sizes[0] / (B * 9);      // 50000
    int npairs = in_sizes[1] / 2;       // 2,000,000
    int P = npairs / B;                 // 500,000
    int nwg = (npairs + PAIRS_PER_BLOCK - 1) / PAIRS_PER_BLOCK;   // 977

    hipMemsetAsync(d_ws, 0, 8, stream);   // ws[0]=pen sum, ws[1]=val sum
    pen_loss_main<<<nwg, 256, 0, stream>>>(tris, idx, ws, npairs, F, P, nwg);
    finalize_kernel<<<1, 1, 0, stream>>>(ws, out);
}

// Round 16
// 61.631 us; speedup vs baseline: 1.4479x; 1.0147x over previous
//
#include <hip/hip_runtime.h>

#define LOSS_EPS 0.001f
#define EPS_PAR 1e-12f
#define EPS_PT 1e-12f

typedef float f32x2 __attribute__((ext_vector_type(2)));
typedef int   i32x2 __attribute__((ext_vector_type(2)));

__device__ __forceinline__ f32x2 vmin2(f32x2 a, f32x2 b) { return __builtin_elementwise_min(a, b); }
__device__ __forceinline__ f32x2 vmax2(f32x2 a, f32x2 b) { return __builtin_elementwise_max(a, b); }
__device__ __forceinline__ f32x2 vclamp01(f32x2 v) {
    return vmin2(vmax2(v, (f32x2)0.0f), (f32x2)1.0f);
}
__device__ __forceinline__ f32x2 vrcp(f32x2 x) {
    f32x2 r; r.x = __builtin_amdgcn_rcpf(x.x); r.y = __builtin_amdgcn_rcpf(x.y); return r;
}
// bit-select: m ? a : b per component (R6-proven form)
__device__ __forceinline__ f32x2 vsel(i32x2 m, f32x2 a, f32x2 b) {
    i32x2 ai = __builtin_bit_cast(i32x2, a);
    i32x2 bi = __builtin_bit_cast(i32x2, b);
    i32x2 r = (ai & m) | (bi & ~m);
    return __builtin_bit_cast(f32x2, r);
}

struct V3p { f32x2 x, y, z; };
__device__ __forceinline__ V3p operator-(V3p a, V3p b) { return {a.x - b.x, a.y - b.y, a.z - b.z}; }
__device__ __forceinline__ V3p operator+(V3p a, V3p b) { return {a.x + b.x, a.y + b.y, a.z + b.z}; }
__device__ __forceinline__ V3p operator*(f32x2 s, V3p a) { return {s * a.x, s * a.y, s * a.z}; }
__device__ __forceinline__ f32x2 dotp(V3p a, V3p b) { return a.x * b.x + a.y * b.y + a.z * b.z; }

// Strength-reduced: t_new/s_new via expanded dots (exact in real arithmetic):
//   dot(r + s*d1, d2) = f + s*b ;  -dot(r - t*d2, d1) = t*b - c
// diff fused as r + s*d1 - t*d2 (fma chain).
__device__ __forceinline__ f32x2 edge_edge_d2(V3p p1, V3p d1, V3p p2, V3p d2,
                                              f32x2 a, f32x2 e, f32x2 ra, f32x2 re) {
    V3p r = p1 - p2;
    f32x2 f = dotp(d2, r);
    f32x2 b = dotp(d1, d2);
    f32x2 c = dotp(d1, r);
    f32x2 denom = a * e - b * b;
    i32x2 par = denom < (f32x2)EPS_PAR;
    f32x2 rd = vrcp(vsel(par, (f32x2)1.0f, denom));
    f32x2 s = (b * f - c * e) * rd;
    f32x2 t = (a * f - b * c) * rd;
    s = vsel(par, (f32x2)0.0f, s);
    f32x2 s_cl = vclamp01(s);
    f32x2 t_cl = vclamp01(t);
    i32x2 rec_t = (s_cl != s) | par;
    f32x2 t_new = vclamp01((f + s_cl * b) * re);
    f32x2 t_fin = vsel(rec_t, t_new, t_cl);
    i32x2 rec_s = (t_cl != t) & ~par & (s_cl == s);
    f32x2 s_new = (t_fin * b - c) * ra;
    f32x2 s_fin = vsel(rec_s, vclamp01(s_new), s_cl);
    V3p diff = { (r.x + s_fin * d1.x) - t_fin * d2.x,
                 (r.y + s_fin * d1.y) - t_fin * d2.y,
                 (r.z + s_fin * d1.z) - t_fin * d2.z };
    return dotp(diff, diff);
}

__device__ __forceinline__ f32x2 ptri3_min_d2(V3p p0, V3p p1, V3p p2,
                                              V3p v0, V3p v1, V3p v2) {
    V3p e0 = v1 - v0;
    V3p e1 = v2 - v0;
    V3p e2t = v2 - v1;
    f32x2 a  = vmax2(dotp(e0, e0), (f32x2)EPS_PT);
    f32x2 b  = dotp(e0, e1);
    f32x2 c  = vmax2(dotp(e1, e1), (f32x2)EPS_PT);
    f32x2 a2 = vmax2(dotp(e2t, e2t), (f32x2)EPS_PT);
    f32x2 det = vmax2(a * c - b * b, (f32x2)EPS_PT);
    f32x2 ra = vrcp(a), rc = vrcp(c), ra2 = vrcp(a2), rdet = vrcp(det);

    f32x2 best = (f32x2)1e30f;
    V3p pts[3] = {p0, p1, p2};
#pragma unroll
    for (int k = 0; k < 3; ++k) {
        V3p p = pts[k];
        V3p w = p - v0;
        f32x2 d = dotp(e0, w);
        f32x2 e = dotp(e1, w);
        f32x2 f = dotp(w, w);
        f32x2 s = b * e - c * d;
        f32x2 t = b * d - a * e;
        i32x2 in_face = (s >= (f32x2)0.0f) & (t >= (f32x2)0.0f) & ((s + t) <= det);
        // |w - s01*e0|^2 = f - s01*(2d - s01*a), clamped >= 0 (fp can round negative)
        f32x2 s01 = vclamp01(d * ra);
        f32x2 d2_e01 = vmax2(f - s01 * (d + d - s01 * a), (f32x2)0.0f);
        f32x2 t02 = vclamp01(e * rc);
        f32x2 d2_e02 = vmax2(f - t02 * (e + e - t02 * c), (f32x2)0.0f);
        V3p w2 = p - v1;
        f32x2 dd2 = dotp(e2t, w2);
        f32x2 u12 = vclamp01(dd2 * ra2);
        V3p u12v = w2 - u12 * e2t;
        f32x2 d2_e12 = dotp(u12v, u12v);
        f32x2 d2_face = vmax2((f * det - (d * s + e * t)) * rdet, (f32x2)0.0f);
        f32x2 d2_edge = vmin2(vmin2(d2_e01, d2_e02), d2_e12);
        best = vmin2(best, vsel(in_face, d2_face, d2_edge));
    }
    return best;
}

// Packed body operating on pre-transposed T arrays (component 0 = even pair, 1 = odd pair).
__device__ __forceinline__ f32x2 body_from_T(const f32x2 T1[9], const f32x2 T2[9], f32x2 vmask) {
    V3p A[3]  = { {T1[0], T1[1], T1[2]}, {T1[3], T1[4], T1[5]}, {T1[6], T1[7], T1[8]} };
    V3p Ac[3] = { {T1[0], T1[3], T1[6]}, {T1[1], T1[4], T1[7]}, {T1[2], T1[5], T1[8]} };
    V3p B[3]  = { {T2[0], T2[1], T2[2]}, {T2[3], T2[4], T2[5]}, {T2[6], T2[7], T2[8]} };
    V3p Bc[3] = { {T2[0], T2[3], T2[6]}, {T2[1], T2[4], T2[7]}, {T2[2], T2[5], T2[8]} };

    f32x2 mind2 = (f32x2)1e30f;
    mind2 = vmin2(mind2, ptri3_min_d2(A[0], A[1], A[2], Bc[0], Bc[1], Bc[2]));
    mind2 = vmin2(mind2, ptri3_min_d2(B[0], B[1], B[2], Ac[0], Ac[1], Ac[2]));

    V3p dA[3] = { A[1] - A[0], A[2] - A[1], A[0] - A[2] };
    V3p dB[3] = { B[1] - B[0], B[2] - B[1], B[0] - B[2] };
    f32x2 la[3], lb[3], rla[3], rlb[3];
#pragma unroll
    for (int k = 0; k < 3; ++k) {
        la[k] = dotp(dA[k], dA[k]); rla[k] = vrcp(la[k]);
        lb[k] = dotp(dB[k], dB[k]); rlb[k] = vrcp(lb[k]);
    }
#pragma unroll
    for (int ii = 0; ii < 3; ++ii) {
#pragma unroll
        for (int jj = 0; jj < 3; ++jj) {
            mind2 = vmin2(mind2, edge_edge_d2(A[ii], dA[ii], B[jj], dB[jj],
                                              la[ii], lb[jj], rla[ii], rlb[jj]));
        }
    }
    f32x2 dist;
    dist.x = __builtin_sqrtf(mind2.x);
    dist.y = __builtin_sqrtf(mind2.y);
    return vmax2((f32x2)LOSS_EPS - dist, (f32x2)0.0f) * vmask;
}

// Plain block reduce + two global atomics. NO fence, NO counter (fence cost ~13us, R14).
__device__ __forceinline__ void block_reduce_atomic(float pen, float val, float* ws) {
#pragma unroll
    for (int off = 32; off > 0; off >>= 1) {
        pen += __shfl_down(pen, off);
        val += __shfl_down(val, off);
    }
    __shared__ float sp[4], sv[4];
    int wid = threadIdx.x >> 6;
    if ((threadIdx.x & 63) == 0) { sp[wid] = pen; sv[wid] = val; }
    __syncthreads();
    if (threadIdx.x == 0) {
        atomicAdd(&ws[0], sp[0] + sp[1] + sp[2] + sp[3]);
        atomicAdd(&ws[1], sv[0] + sv[1] + sv[2] + sv[3]);
    }
}

#define PPT 8                         // pairs per thread (4 packed bodies) — R6-proven
#define PAIRS_PER_BLOCK (256 * PPT)   // 2048

// Direct gathers from the original 36B rows (R15-proven; packed table is not needed).
__global__ void __launch_bounds__(256)
pen_loss_main(const float* __restrict__ tris, const int* __restrict__ idx,
              float* __restrict__ ws, int npairs, int F, int P, int nwg) {
    // Bijective XCD chunk swizzle (m204).
    int pb = blockIdx.x;
    int x = pb & 7, j = pb >> 3;
    int q8 = nwg >> 3, r8 = nwg & 7;
    int start = (x < r8) ? x * (q8 + 1) : r8 * (q8 + 1) + (x - r8) * q8;
    int lb = start + j;
    int tid = (int)threadIdx.x;
    int p0 = lb * PAIRS_PER_BLOCK + tid;

    // 1) All idx loads upfront (coalesced, nontemporal: keep L2 for the table).
    int o1[PPT], o2[PPT];
    float vm[PPT];
#pragma unroll
    for (int k = 0; k < PPT; ++k) {
        int p = p0 + k * 256;
        int pc = min(p, npairs - 1);
        long long pr = __builtin_nontemporal_load((const long long*)idx + pc);
        int rx = (int)(pr & 0xffffffffLL);
        int ry = (int)(pr >> 32);
        vm[k] = (p < npairs && rx >= 0) ? 1.0f : 0.0f;
        int b = (pc >= P) + (pc >= 2 * P) + (pc >= 3 * P);   // pc / P without idiv
        int base = b * F;
        o1[k] = (base + max(rx, 0)) * 9;
        o2[k] = (base + max(ry, 0)) * 9;
    }

    // Staging for one body (2 pairs): per triangle 2x dwordx4 + 1 dword.
    // PACKT consumes it; the next LOADBODY refills while the body computes.
    float4 qAe0, qAe1, qBe0, qBe1, qAo0, qAo1, qBo0, qBo1;
    float  sAe, sBe, sAo, sBo;

#define LOADBODY(m) do {                                                      \
        const int ev = 2 * (m), od = 2 * (m) + 1;                             \
        qAe0 = *(const float4*)(tris + o1[ev]);                               \
        qAe1 = *(const float4*)(tris + o1[ev] + 4);                           \
        sAe  = tris[o1[ev] + 8];                                              \
        qBe0 = *(const float4*)(tris + o2[ev]);                               \
        qBe1 = *(const float4*)(tris + o2[ev] + 4);                           \
        sBe  = tris[o2[ev] + 8];                                              \
        qAo0 = *(const float4*)(tris + o1[od]);                               \
        qAo1 = *(const float4*)(tris + o1[od] + 4);                           \
        sAo  = tris[o1[od] + 8];                                              \
        qBo0 = *(const float4*)(tris + o2[od]);                               \
        qBo1 = *(const float4*)(tris + o2[od] + 4);                           \
        sBo  = tris[o2[od] + 8];                                              \
    } while (0)

#define PACKT(T1, T2) do {                                                    \
        T1[0] = (f32x2){qAe0.x, qAo0.x}; T1[1] = (f32x2){qAe0.y, qAo0.y};     \
        T1[2] = (f32x2){qAe0.z, qAo0.z}; T1[3] = (f32x2){qAe0.w, qAo0.w};     \
        T1[4] = (f32x2){qAe1.x, qAo1.x}; T1[5] = (f32x2){qAe1.y, qAo1.y};     \
        T1[6] = (f32x2){qAe1.z, qAo1.z}; T1[7] = (f32x2){qAe1.w, qAo1.w};     \
        T1[8] = (f32x2){sAe, sAo};                                            \
        T2[0] = (f32x2){qBe0.x, qBo0.x}; T2[1] = (f32x2){qBe0.y, qBo0.y};     \
        T2[2] = (f32x2){qBe0.z, qBo0.z}; T2[3] = (f32x2){qBe0.w, qBo0.w};     \
        T2[4] = (f32x2){qBe1.x, qBo1.x}; T2[5] = (f32x2){qBe1.y, qBo1.y};     \
        T2[6] = (f32x2){qBe1.z, qBo1.z}; T2[7] = (f32x2){qBe1.w, qBo1.w};     \
        T2[8] = (f32x2){sBe, sBo};                                            \
    } while (0)

    LOADBODY(0);
    f32x2 pen2 = (f32x2)0.0f;
#pragma unroll
    for (int m = 0; m < PPT / 2; ++m) {
        f32x2 T1[9], T2[9];
        PACKT(T1, T2);                     // consumes staging (waits loads), frees it
        if (m < PPT / 2 - 1) LOADBODY(m + 1);  // next body's gathers fly under the body
        f32x2 vmm = {vm[2 * m], vm[2 * m + 1]};
        pen2 += body_from_T(T1, T2, vmm);
    }
#undef LOADBODY
#undef PACKT

    float pen_s = pen2.x + pen2.y;
    float val_s = 0.0f;
#pragma unroll
    for (int k = 0; k < PPT; ++k) val_s += vm[k];
    block_reduce_atomic(pen_s, val_s, ws);
}

__global__ void finalize_kernel(const float* __restrict__ ws, float* __restrict__ out) {
    out[0] = ws[0] / fmaxf(ws[1], 1.0f);
}

extern "C" void kernel_launch(void* const* d_in, const int* in_sizes, int n_in,
                              void* d_out, int out_size, void* d_ws, size_t ws_size,
                              hipStream_t stream) {
    const float* tris = (const float*)d_in[0];
    const int* idx = (const int*)d_in[1];
    float* out = (float*)d_out;
    float* ws = (float*)d_ws;

    const int B = 4;
    int F = in_sizes[0] / (B * 9);      // 50000
    int npairs = in_sizes[1] / 2;       // 2,000,000
    int P = npairs / B;                 // 500,000
    int nwg = (npairs + PAIRS_PER_BLOCK - 1) / PAIRS_PER_BLOCK;   // 977

    hipMemsetAsync(d_ws, 0, 8, stream);   // ws[0]=pen sum, ws[1]=val sum
    pen_loss_main<<<nwg, 256, 0, stream>>>(tris, idx, ws, npairs, F, P, nwg);
    finalize_kernel<<<1, 1, 0, stream>>>(ws, out);
}